// Round 1
// baseline (2639.011 us; speedup 1.0000x reference)
//
#include <hip/hip_runtime.h>

typedef unsigned short u16;
typedef unsigned int u32;
using bf16x8 = __attribute__((ext_vector_type(8))) short;
using f32x4 = __attribute__((ext_vector_type(4))) float;

constexpr int kL = 8192;
constexpr int kDIM = 256;
constexpr int kDI = 512;
constexpr int kNB = 8;
constexpr float kEPS = 1e-3f;

__device__ __forceinline__ u16 f2b(float f) {
  u32 x = __builtin_bit_cast(u32, f);
  x += 0x7fffu + ((x >> 16) & 1u);
  return (u16)(x >> 16);
}
__device__ __forceinline__ float b2f(u16 u) {
  return __builtin_bit_cast(float, (u32)u << 16);
}
__device__ __forceinline__ float sigm(float x) { return 1.f / (1.f + __expf(-x)); }

__device__ __forceinline__ void async_cp16(const void* g, void* l) {
  __builtin_amdgcn_global_load_lds((const __attribute__((address_space(1))) u32*)g,
                                   (__attribute__((address_space(3))) u32*)l, 16, 0, 0);
}

// ---------------- generic f32 -> bf16 convert ----------------
__global__ void cvt_bf16_k(const float* __restrict__ s, u16* __restrict__ d, int n) {
  for (int i = blockIdx.x * blockDim.x + threadIdx.x; i < n; i += gridDim.x * blockDim.x)
    d[i] = f2b(s[i]);
}

// dproj (NB,NE,DIM,INNER) -> W2 (NB, DIM, NE*INNER) bf16
__global__ void cvt_dproj_k(const float* __restrict__ s, u16* __restrict__ d) {
  const int total = kNB * 4 * kDIM * 512;
  for (int i = blockIdx.x * blockDim.x + threadIdx.x; i < total; i += gridDim.x * blockDim.x) {
    int b = i >> 19;
    int r = i & 524287;
    int e = r >> 17;
    int r2 = r & 131071;
    int n = r2 >> 9;
    int j = r2 & 511;
    d[(size_t)b * 524288 + (size_t)n * 2048 + e * 512 + j] = f2b(s[i]);
  }
}

// x (DIM, L) f32 -> xT (L, DIM) bf16
__global__ __launch_bounds__(256) void transpose_x_k(const float* __restrict__ x, u16* __restrict__ xT) {
  __shared__ float tile[32][33];
  int l0 = blockIdx.x * 32, d0 = blockIdx.y * 32;
  int tx = threadIdx.x, ty = threadIdx.y;
  #pragma unroll
  for (int i = 0; i < 32; i += 8)
    tile[ty + i][tx] = x[(size_t)(d0 + ty + i) * kL + l0 + tx];
  __syncthreads();
  #pragma unroll
  for (int i = 0; i < 32; i += 8)
    xT[(size_t)(l0 + ty + i) * kDIM + d0 + tx] = f2b(tile[tx][ty + i]);
}

// ---------------- MFMA GEMM: C(MxN) = A(MxK,bf16) @ W(NxK,bf16)^T ----------------
// mode 0: f32 store; 1: f32 accumulate (+=); 2: bf16 store; 3: silu -> bf16 store
__global__ __launch_bounds__(256) void gemm_k(
    const u16* __restrict__ A, int lda,
    const u16* __restrict__ W, int ldw,
    void* __restrict__ C, int ldc,
    int N, int K, int mode)
{
  __shared__ u16 As[128 * 64];
  __shared__ u16 Bs[128 * 64];
  const int tid = threadIdx.x;
  const int lane = tid & 63;
  const int wave = tid >> 6;
  const int bm = blockIdx.x * 128;
  const int bn = blockIdx.y * 128;
  const int wr = (wave >> 1) * 64;
  const int wc = (wave & 1) * 64;

  f32x4 acc[4][4];
  #pragma unroll
  for (int r = 0; r < 4; ++r)
    #pragma unroll
    for (int c = 0; c < 4; ++c)
      acc[r][c] = f32x4{0.f, 0.f, 0.f, 0.f};

  for (int k0 = 0; k0 < K; k0 += 64) {
    #pragma unroll
    for (int it = 0; it < 4; ++it) {
      int flat = (it * 256 + tid) * 8;
      int r = flat >> 6, cc = flat & 63;
      async_cp16(A + (size_t)(bm + r) * lda + k0 + cc, &As[flat]);
    }
    #pragma unroll
    for (int it = 0; it < 4; ++it) {
      int flat = (it * 256 + tid) * 8;
      int r = flat >> 6, cc = flat & 63;
      int n = bn + r;
      if (n > N - 1) n = N - 1;
      async_cp16(W + (size_t)n * ldw + k0 + cc, &Bs[flat]);
    }
    __syncthreads();
    const int mrow = lane & 15;
    #pragma unroll
    for (int kk = 0; kk < 64; kk += 32) {
      const int koff = kk + (lane >> 4) * 8;
      bf16x8 a[4], b[4];
      #pragma unroll
      for (int r = 0; r < 4; ++r)
        a[r] = *(const bf16x8*)&As[(wr + r * 16 + mrow) * 64 + koff];
      #pragma unroll
      for (int c = 0; c < 4; ++c)
        b[c] = *(const bf16x8*)&Bs[(wc + c * 16 + mrow) * 64 + koff];
      #pragma unroll
      for (int r = 0; r < 4; ++r)
        #pragma unroll
        for (int c = 0; c < 4; ++c)
          acc[r][c] = __builtin_amdgcn_mfma_f32_16x16x32_bf16(a[r], b[c], acc[r][c], 0, 0, 0);
    }
    __syncthreads();
  }

  const int colb = bn + wc + (lane & 15);
  const int rowb = bm + wr + ((lane >> 4) << 2);
  if (mode == 0) {
    float* Cf = (float*)C;
    #pragma unroll
    for (int r = 0; r < 4; ++r)
      #pragma unroll
      for (int c = 0; c < 4; ++c) {
        int col = colb + c * 16;
        if (col >= N) continue;
        #pragma unroll
        for (int i = 0; i < 4; ++i)
          Cf[(size_t)(rowb + r * 16 + i) * ldc + col] = acc[r][c][i];
      }
  } else if (mode == 1) {
    float* Cf = (float*)C;
    #pragma unroll
    for (int r = 0; r < 4; ++r)
      #pragma unroll
      for (int c = 0; c < 4; ++c) {
        int col = colb + c * 16;
        if (col >= N) continue;
        #pragma unroll
        for (int i = 0; i < 4; ++i) {
          size_t off = (size_t)(rowb + r * 16 + i) * ldc + col;
          Cf[off] += acc[r][c][i];
        }
      }
  } else if (mode == 2) {
    u16* Cb = (u16*)C;
    #pragma unroll
    for (int r = 0; r < 4; ++r)
      #pragma unroll
      for (int c = 0; c < 4; ++c) {
        int col = colb + c * 16;
        if (col >= N) continue;
        #pragma unroll
        for (int i = 0; i < 4; ++i)
          Cb[(size_t)(rowb + r * 16 + i) * ldc + col] = f2b(acc[r][c][i]);
      }
  } else {
    u16* Cb = (u16*)C;
    #pragma unroll
    for (int r = 0; r < 4; ++r)
      #pragma unroll
      for (int c = 0; c < 4; ++c) {
        int col = colb + c * 16;
        if (col >= N) continue;
        #pragma unroll
        for (int i = 0; i < 4; ++i) {
          float v = acc[r][c][i];
          Cb[(size_t)(rowb + r * 16 + i) * ldc + col] = f2b(v * sigm(v));
        }
      }
  }
}

// ---------------- block-wide sum over 256 threads ----------------
__device__ __forceinline__ float block_sum256(float v) {
  #pragma unroll
  for (int o = 32; o > 0; o >>= 1) v += __shfl_down(v, o);
  __shared__ float red[4];
  if ((threadIdx.x & 63) == 0) red[threadIdx.x >> 6] = v;
  __syncthreads();
  return red[0] + red[1] + red[2] + red[3];
}

// rmsnorm(h)*w -> bf16 (block = one row of 256)
__global__ __launch_bounds__(256) void rms_a_k(const float* __restrict__ h, const float* __restrict__ w,
                                               u16* __restrict__ hn) {
  const int l = blockIdx.x, t = threadIdx.x;
  const float v = h[(size_t)l * kDIM + t];
  const float ssum = block_sum256(v * v);
  const float r = rsqrtf(ssum * (1.f / 256.f) + kEPS);
  hn[(size_t)l * kDIM + t] = f2b(w[t] * v * r);
}

// h = h + rmsnorm(moe)*w ; also emit bf16 copy of new h
__global__ __launch_bounds__(256) void rms_f_add_k(const float* __restrict__ moe, const float* __restrict__ w,
                                                   float* __restrict__ h, u16* __restrict__ hb2) {
  const int l = blockIdx.x, t = threadIdx.x;
  const float m = moe[(size_t)l * kDIM + t];
  const float ssum = block_sum256(m * m);
  const float r = rsqrtf(ssum * (1.f / 256.f) + kEPS);
  const float hv = h[(size_t)l * kDIM + t] + w[t] * m * r;
  h[(size_t)l * kDIM + t] = hv;
  hb2[(size_t)l * kDIM + t] = f2b(hv);
}

// causal depthwise conv (4 taps) + bias + silu; also silu of res half
__global__ __launch_bounds__(256) void conv_silu_k(const float* __restrict__ xz, const float* __restrict__ cw,
                                                   const float* __restrict__ cb, float* __restrict__ xc,
                                                   u16* __restrict__ xcb, float* __restrict__ sres) {
  const int idx = blockIdx.x * 256 + threadIdx.x;  // L*DI
  const int l = idx >> 9, d = idx & 511;
  float acc = cb[d];
  #pragma unroll
  for (int j = 0; j < 4; ++j) {
    int ll = l - 3 + j;
    if (ll >= 0) acc += cw[d * 4 + j] * xz[(size_t)ll * 1024 + d];
  }
  const float s = acc * sigm(acc);
  xc[idx] = s;
  xcb[idx] = f2b(s);
  const float rr = xz[(size_t)l * 1024 + 512 + d];
  sres[idx] = rr * sigm(rr);
}

// delta = softplus(dr @ dtw^T + dtb)
__global__ __launch_bounds__(256) void dt_softplus_k(const float* __restrict__ xdbl, const float* __restrict__ dtw,
                                                     const float* __restrict__ dtb, float* __restrict__ delta) {
  const int idx = blockIdx.x * 256 + threadIdx.x;  // L*DI
  const int l = idx >> 9, d = idx & 511;
  float acc = dtb[d];
  const float* xr = xdbl + (size_t)l * 48;
  const float* wr = dtw + (size_t)d * 16;
  #pragma unroll
  for (int r = 0; r < 16; ++r) acc += xr[r] * wr[r];
  delta[idx] = fmaxf(acc, 0.f) + log1pf(__expf(-fabsf(acc)));
}

// ---------------- 3-phase chunked selective scan (128 chunks x 64 steps) ----------------
__global__ __launch_bounds__(256) void scan_a_k(const float* __restrict__ delta, const float* __restrict__ xdbl,
                                                const float* __restrict__ xc, const float* __restrict__ A_log,
                                                float* __restrict__ aprod, float* __restrict__ bacc) {
  const int c = blockIdx.x;
  const int d = blockIdx.y * 256 + threadIdx.x;
  const int l0 = c * 64;
  __shared__ float Bsh[64][16];
  for (int i = threadIdx.x; i < 1024; i += 256) {
    int lr = i >> 4, n = i & 15;
    Bsh[lr][n] = xdbl[(size_t)(l0 + lr) * 48 + 16 + n];
  }
  __syncthreads();
  float Ad[16];
  #pragma unroll
  for (int n = 0; n < 16; ++n) Ad[n] = -__expf(A_log[d * 16 + n]);
  float s[16], ap[16];
  #pragma unroll
  for (int n = 0; n < 16; ++n) { s[n] = 0.f; ap[n] = 1.f; }
  for (int lr = 0; lr < 64; ++lr) {
    const int l = l0 + lr;
    const float dl = delta[(size_t)l * 512 + d];
    const float du = dl * xc[(size_t)l * 512 + d];
    #pragma unroll
    for (int n = 0; n < 16; ++n) {
      const float a = __expf(dl * Ad[n]);
      s[n] = fmaf(a, s[n], du * Bsh[lr][n]);
      ap[n] *= a;
    }
  }
  const int o = (c * 512 + d) * 16;
  #pragma unroll
  for (int n = 0; n < 16; ++n) { aprod[o + n] = ap[n]; bacc[o + n] = s[n]; }
}

__global__ __launch_bounds__(256) void scan_b_k(const float* __restrict__ aprod, const float* __restrict__ bacc,
                                                float* __restrict__ sinit) {
  const int t = blockIdx.x * 256 + threadIdx.x;  // DI*NS = 8192
  float s = 0.f;
  for (int c = 0; c < 128; ++c) {
    sinit[(size_t)c * 8192 + t] = s;
    s = fmaf(aprod[(size_t)c * 8192 + t], s, bacc[(size_t)c * 8192 + t]);
  }
}

__global__ __launch_bounds__(256) void scan_c_k(const float* __restrict__ delta, const float* __restrict__ xdbl,
                                                const float* __restrict__ xc, const float* __restrict__ A_log,
                                                const float* __restrict__ sinit, const float* __restrict__ sres,
                                                const float* __restrict__ Dp, u16* __restrict__ yv) {
  const int c = blockIdx.x;
  const int d = blockIdx.y * 256 + threadIdx.x;
  const int l0 = c * 64;
  __shared__ float Bsh[64][16];
  __shared__ float Csh[64][16];
  for (int i = threadIdx.x; i < 1024; i += 256) {
    int lr = i >> 4, n = i & 15;
    Bsh[lr][n] = xdbl[(size_t)(l0 + lr) * 48 + 16 + n];
    Csh[lr][n] = xdbl[(size_t)(l0 + lr) * 48 + 32 + n];
  }
  __syncthreads();
  float Ad[16];
  #pragma unroll
  for (int n = 0; n < 16; ++n) Ad[n] = -__expf(A_log[d * 16 + n]);
  float s[16];
  const int o = (c * 512 + d) * 16;
  #pragma unroll
  for (int n = 0; n < 16; ++n) s[n] = sinit[o + n];
  const float Dd = Dp[d];
  for (int lr = 0; lr < 64; ++lr) {
    const int l = l0 + lr;
    const float dl = delta[(size_t)l * 512 + d];
    const float xv = xc[(size_t)l * 512 + d];
    const float du = dl * xv;
    float y = 0.f;
    #pragma unroll
    for (int n = 0; n < 16; ++n) {
      const float a = __expf(dl * Ad[n]);
      s[n] = fmaf(a, s[n], du * Bsh[lr][n]);
      y = fmaf(s[n], Csh[lr][n], y);
    }
    y = (y + xv * Dd) * sres[(size_t)l * 512 + d];
    yv[(size_t)l * 512 + d] = f2b(y);
  }
}

// router: scores, top-2 softmax weights; also bf16 copy of h
__global__ __launch_bounds__(256) void router_k(const float* __restrict__ h, const float* __restrict__ gw,
                                                float* __restrict__ we, u16* __restrict__ hb) {
  const int l = blockIdx.x * 4 + (threadIdx.x >> 6);
  const int lane = threadIdx.x & 63;
  const float4 v = reinterpret_cast<const float4*>(h + (size_t)l * 256)[lane];
  ushort4 hv = make_ushort4(f2b(v.x), f2b(v.y), f2b(v.z), f2b(v.w));
  reinterpret_cast<ushort4*>(hb + (size_t)l * 256)[lane] = hv;
  float p[4];
  #pragma unroll
  for (int e = 0; e < 4; ++e) {
    const float4 g = reinterpret_cast<const float4*>(gw + (size_t)e * 256)[lane];
    p[e] = v.x * g.x + v.y * g.y + v.z * g.z + v.w * g.w;
  }
  #pragma unroll
  for (int o = 32; o > 0; o >>= 1) {
    p[0] += __shfl_down(p[0], o);
    p[1] += __shfl_down(p[1], o);
    p[2] += __shfl_down(p[2], o);
    p[3] += __shfl_down(p[3], o);
  }
  if (lane == 0) {
    int i0 = 0;
    #pragma unroll
    for (int e = 1; e < 4; ++e) if (p[e] > p[i0]) i0 = e;
    int i1 = -1;
    #pragma unroll
    for (int e = 0; e < 4; ++e) {
      if (e == i0) continue;
      if (i1 < 0 || p[e] > p[i1]) i1 = e;
    }
    const float t = __expf(p[i1] - p[i0]);
    const float w0 = 1.f / (1.f + t);
    const float w1 = t / (1.f + t);
    float o[4] = {0.f, 0.f, 0.f, 0.f};
    o[i0] = w0; o[i1] = w1;
    reinterpret_cast<float4*>(we)[l] = make_float4(o[0], o[1], o[2], o[3]);
  }
}

// ts = silu(g)*u*we  (bf16 in/out), 4 elems/thread
__global__ __launch_bounds__(256) void mix_glu_k(const u16* __restrict__ g, const u16* __restrict__ u,
                                                 const float* __restrict__ we, u16* __restrict__ ts) {
  const int i4 = blockIdx.x * 256 + threadIdx.x;  // L*2048/4
  const int base = i4 * 4;
  const int l = base >> 11;
  const int m = base & 2047;
  const float w = we[l * 4 + (m >> 9)];
  const ushort4 gv = reinterpret_cast<const ushort4*>(g)[i4];
  const ushort4 uv = reinterpret_cast<const ushort4*>(u)[i4];
  float g0 = b2f(gv.x), g1 = b2f(gv.y), g2 = b2f(gv.z), g3 = b2f(gv.w);
  ushort4 o;
  o.x = f2b(g0 * sigm(g0) * b2f(uv.x) * w);
  o.y = f2b(g1 * sigm(g1) * b2f(uv.y) * w);
  o.z = f2b(g2 * sigm(g2) * b2f(uv.z) * w);
  o.w = f2b(g3 * sigm(g3) * b2f(uv.w) * w);
  reinterpret_cast<ushort4*>(ts)[i4] = o;
}

// out[o,l] = sigmoid(g2[l,o])
__global__ __launch_bounds__(256) void sig_t_k(const float* __restrict__ g2, float* __restrict__ out) {
  __shared__ float tl[32][33];
  const int l0 = blockIdx.x * 32;
  const int t = threadIdx.x;
  const int r = t >> 5, c = t & 31;
  #pragma unroll
  for (int j = 0; j < 4; ++j) {
    int li = r * 4 + j;
    tl[li][c] = g2[(size_t)(l0 + li) * 32 + c];
  }
  __syncthreads();
  #pragma unroll
  for (int j = 0; j < 4; ++j) {
    int oo = r * 4 + j;
    out[(size_t)oo * kL + l0 + c] = sigm(tl[c][oo]);
  }
}

extern "C" void kernel_launch(void* const* d_in, const int* in_sizes, int n_in,
                              void* d_out, int out_size, void* d_ws, size_t ws_size,
                              hipStream_t stream) {
  const float* x        = (const float*)d_in[0];
  const float* lin_w    = (const float*)d_in[1];
  const float* in_proj  = (const float*)d_in[2];
  const float* conv_w   = (const float*)d_in[3];
  const float* conv_b   = (const float*)d_in[4];
  const float* x_proj   = (const float*)d_in[5];
  const float* dt_w     = (const float*)d_in[6];
  const float* dt_b     = (const float*)d_in[7];
  const float* A_log    = (const float*)d_in[8];
  const float* D_param  = (const float*)d_in[9];
  const float* out_proj = (const float*)d_in[10];
  const float* gate_w   = (const float*)d_in[11];
  const float* gproj    = (const float*)d_in[12];
  const float* uproj    = (const float*)d_in[13];
  const float* dproj    = (const float*)d_in[14];
  const float* rms_a_w  = (const float*)d_in[15];
  const float* rms_f_w  = (const float*)d_in[16];
  const float* head_w1  = (const float*)d_in[17];
  const float* head_w2  = (const float*)d_in[18];

  char* p = (char*)d_ws;
  auto alloc = [&](size_t bytes) -> char* {
    char* r = p;
    p += (bytes + 255) & ~(size_t)255;
    return r;
  };

  // bf16 weight pool
  u16* lin_b = (u16*)alloc(65536 * 2);
  u16* ipw_b = (u16*)alloc((size_t)2097152 * 2);
  u16* xpw_b = (u16*)alloc((size_t)196608 * 2);
  u16* opw_b = (u16*)alloc((size_t)1048576 * 2);
  u16* gpw_b = (u16*)alloc((size_t)4194304 * 2);
  u16* upw_b = (u16*)alloc((size_t)4194304 * 2);
  u16* dpw_b = (u16*)alloc((size_t)4194304 * 2);
  u16* hw1_b = (u16*)alloc(65536 * 2);
  u16* hw2_b = (u16*)alloc(8192 * 2);

  // activations
  u16* xT   = (u16*)alloc((size_t)kL * kDIM * 2);
  float* h  = (float*)alloc((size_t)kL * kDIM * 4);
  u16* hn   = (u16*)alloc((size_t)kL * kDIM * 2);
  u16* hb   = (u16*)alloc((size_t)kL * kDIM * 2);
  u16* hb2  = (u16*)alloc((size_t)kL * kDIM * 2);
  float* we = (float*)alloc((size_t)kL * 4 * 4);
  float* xdbl = (float*)alloc((size_t)kL * 48 * 4);
  float* g2o  = (float*)alloc((size_t)kL * 32 * 4);
  u16* fb   = (u16*)alloc((size_t)kL * kDIM * 2);
  u16* h2b  = (u16*)alloc((size_t)kL * kDIM * 2);
  char* un  = alloc((size_t)67108864);          // xz f32 (32MB) | g_b,u_b bf16 (32MB each)
  float* xz = (float*)un;
  u16* g_b  = (u16*)un;
  u16* u_b  = (u16*)(un + 33554432);
  float* delta = (float*)alloc((size_t)kL * kDI * 4);  // ts aliases delta+xc (contiguous)
  float* xc    = (float*)alloc((size_t)kL * kDI * 4);
  u16* ts      = (u16*)delta;
  float* sres  = (float*)alloc((size_t)kL * kDI * 4);
  u16* xcb     = (u16*)alloc((size_t)kL * kDI * 2);
  u16* yv      = (u16*)alloc((size_t)kL * kDI * 2);
  float* aprod = (float*)alloc((size_t)128 * 8192 * 4);
  float* bacc  = (float*)alloc((size_t)128 * 8192 * 4);
  float* sinit = (float*)alloc((size_t)128 * 8192 * 4);
  float* moe   = (float*)alloc((size_t)kL * kDIM * 4);

  if ((size_t)(p - (char*)d_ws) > ws_size) return;  // fail loudly (output stays poisoned)

  // weight conversion
  cvt_bf16_k<<<512, 256, 0, stream>>>(lin_w, lin_b, 65536);
  cvt_bf16_k<<<2048, 256, 0, stream>>>(in_proj, ipw_b, 2097152);
  cvt_bf16_k<<<512, 256, 0, stream>>>(x_proj, xpw_b, 196608);
  cvt_bf16_k<<<1024, 256, 0, stream>>>(out_proj, opw_b, 1048576);
  cvt_bf16_k<<<2048, 256, 0, stream>>>(gproj, gpw_b, 4194304);
  cvt_bf16_k<<<2048, 256, 0, stream>>>(uproj, upw_b, 4194304);
  cvt_dproj_k<<<2048, 256, 0, stream>>>(dproj, dpw_b);
  cvt_bf16_k<<<512, 256, 0, stream>>>(head_w1, hw1_b, 65536);
  cvt_bf16_k<<<32, 256, 0, stream>>>(head_w2, hw2_b, 8192);

  transpose_x_k<<<dim3(kL / 32, kDIM / 32), dim3(32, 8), 0, stream>>>(x, xT);

  auto gemm = [&](const u16* A, int lda, const u16* W, int ldw, void* C, int ldc, int N, int K, int mode) {
    gemm_k<<<dim3(kL / 128, (N + 127) / 128), 256, 0, stream>>>(A, lda, W, ldw, C, ldc, N, K, mode);
  };

  // h = xT @ lin_w^T
  gemm(xT, 256, lin_b, 256, h, 256, 256, 256, 0);

  for (int i = 0; i < kNB; ++i) {
    rms_a_k<<<kL, 256, 0, stream>>>(h, rms_a_w, hn);
    gemm(hn, 256, ipw_b + (size_t)i * 262144, 256, xz, 1024, 1024, 256, 0);
    conv_silu_k<<<kL * kDI / 256, 256, 0, stream>>>(xz, conv_w + (size_t)i * 2048,
                                                    conv_b + (size_t)i * 512, xc, xcb, sres);
    gemm(xcb, 512, xpw_b + (size_t)i * 24576, 512, xdbl, 48, 48, 512, 0);
    dt_softplus_k<<<kL * kDI / 256, 256, 0, stream>>>(xdbl, dt_w + (size_t)i * 8192,
                                                      dt_b + (size_t)i * 512, delta);
    scan_a_k<<<dim3(128, 2), 256, 0, stream>>>(delta, xdbl, xc, A_log + (size_t)i * 8192, aprod, bacc);
    scan_b_k<<<32, 256, 0, stream>>>(aprod, bacc, sinit);
    scan_c_k<<<dim3(128, 2), 256, 0, stream>>>(delta, xdbl, xc, A_log + (size_t)i * 8192, sinit,
                                               sres, D_param + (size_t)i * 512, yv);
    gemm(yv, 512, opw_b + (size_t)i * 131072, 512, h, 256, 256, 512, 1);  // h += mamba out
    router_k<<<kL / 4, 256, 0, stream>>>(h, gate_w + (size_t)i * 1024, we, hb);
    gemm(hb, 256, gpw_b + (size_t)i * 524288, 256, g_b, 2048, 2048, 256, 2);
    gemm(hb, 256, upw_b + (size_t)i * 524288, 256, u_b, 2048, 2048, 256, 2);
    mix_glu_k<<<kL * 2048 / 1024, 256, 0, stream>>>(g_b, u_b, we, ts);
    gemm(ts, 2048, dpw_b + (size_t)i * 524288, 2048, moe, 256, 256, 2048, 0);
    rms_f_add_k<<<kL, 256, 0, stream>>>(moe, rms_f_w, h, hb2);
  }

  gemm(hb2, 256, lin_b, 256, h2b, 256, 256, 256, 2);
  gemm(h2b, 256, hw1_b, 256, fb, 256, 256, 256, 3);
  gemm(fb, 256, hw2_b, 256, g2o, 32, 32, 256, 0);
  sig_t_k<<<kL / 32, 256, 0, stream>>>(g2o, (float*)d_out);
}